// Round 5
// baseline (240.884 us; speedup 1.0000x reference)
//
#include <hip/hip_runtime.h>
#include <hip/hip_bf16.h>

// ---------------------------------------------------------------------------
// ViLLayer forward, round 4:
//   - global V^T buffer (LDS-tiled transpose) -> PV B-frags are 16B vector
//     loads (was 96 scalar 2B gathers per j-tile).
//   - part kernel: no barriers (per-wave P buffer), causal early-break,
//     float4 partial layout.
//   - conv_silu vectorized to float4 channels.
// ---------------------------------------------------------------------------

#define B_     4
#define S_     1024
#define DIM_   384
#define INNER_ 768
#define NHM_   4
#define DH_    192
#define NTOK   (B_*S_)      // 4096
#define SLOTS_ 40           // sum over t of ceil((t+1)/4)

typedef __attribute__((ext_vector_type(8))) __bf16 bf16x8v;
typedef __attribute__((ext_vector_type(4))) float  f32x4;

static __device__ __forceinline__ f32x4 mfma16(bf16x8v a, bf16x8v b, f32x4 c) {
  return __builtin_amdgcn_mfma_f32_16x16x32_bf16(a, b, c, 0, 0, 0);
}

// ---------------- cast fp32 -> bf16 (vectorized) ---------------------------
__global__ __launch_bounds__(256) void cast_bf16_k(
    const float* __restrict__ in, __hip_bfloat16* __restrict__ out, int n4)
{
  const int i = blockIdx.x * 256 + threadIdx.x;
  if (i >= n4) return;
  const float4 v = *(const float4*)&in[i * 4];
  out[i * 4 + 0] = __float2bfloat16(v.x);
  out[i * 4 + 1] = __float2bfloat16(v.y);
  out[i * 4 + 2] = __float2bfloat16(v.z);
  out[i * 4 + 3] = __float2bfloat16(v.w);
}

// ---------------- up-proj: bf16 MFMA GEMM ----------------------------------
__global__ __launch_bounds__(256) void gemm_up_k(
    const __hip_bfloat16* __restrict__ xb, const __hip_bfloat16* __restrict__ Wb,
    const float* __restrict__ bias, float* __restrict__ C)
{
  const int n0 = blockIdx.x * 128, m0 = blockIdx.y * 64;
  const int wave = threadIdx.x >> 6, lane = threadIdx.x & 63;
  const int lrow = lane & 15, lgrp = lane >> 4;
  const __hip_bfloat16* xr = xb + (size_t)(m0 + wave * 16 + lrow) * DIM_;
  f32x4 acc[8];
  #pragma unroll
  for (int nt = 0; nt < 8; ++nt) acc[nt] = f32x4{0.f, 0.f, 0.f, 0.f};
  for (int k0 = 0; k0 < DIM_; k0 += 32) {
    const bf16x8v af = *(const bf16x8v*)&xr[k0 + lgrp * 8];
    #pragma unroll
    for (int nt = 0; nt < 8; ++nt) {
      const bf16x8v bf = *(const bf16x8v*)
          &Wb[(size_t)(n0 + nt * 16 + lrow) * DIM_ + k0 + lgrp * 8];
      acc[nt] = mfma16(af, bf, acc[nt]);
    }
  }
  #pragma unroll
  for (int nt = 0; nt < 8; ++nt) {
    const int n = n0 + nt * 16 + lrow;
    const float bv = bias[n];
    #pragma unroll
    for (int r = 0; r < 4; ++r) {
      const int m = m0 + wave * 16 + lgrp * 4 + r;
      C[(size_t)m * 1536 + n] = acc[nt][r] + bv;
    }
  }
}

// ---------------- down-proj: bf16 MFMA GEMM --------------------------------
__global__ __launch_bounds__(256) void gemm_down_k(
    const __hip_bfloat16* __restrict__ hsb, const __hip_bfloat16* __restrict__ Wdb,
    const float* __restrict__ bias, float* __restrict__ C)
{
  const int n0 = blockIdx.x * 128, m0 = blockIdx.y * 64;
  const int wave = threadIdx.x >> 6, lane = threadIdx.x & 63;
  const int lrow = lane & 15, lgrp = lane >> 4;
  const __hip_bfloat16* ar = hsb + (size_t)(m0 + wave * 16 + lrow) * INNER_;
  f32x4 acc[8];
  #pragma unroll
  for (int nt = 0; nt < 8; ++nt) acc[nt] = f32x4{0.f, 0.f, 0.f, 0.f};
  for (int k0 = 0; k0 < INNER_; k0 += 32) {
    const bf16x8v af = *(const bf16x8v*)&ar[k0 + lgrp * 8];
    #pragma unroll
    for (int nt = 0; nt < 8; ++nt) {
      const bf16x8v bf = *(const bf16x8v*)
          &Wdb[(size_t)(n0 + nt * 16 + lrow) * INNER_ + k0 + lgrp * 8];
      acc[nt] = mfma16(af, bf, acc[nt]);
    }
  }
  #pragma unroll
  for (int nt = 0; nt < 8; ++nt) {
    const int n = n0 + nt * 16 + lrow;
    const float bv = bias[n];
    #pragma unroll
    for (int r = 0; r < 4; ++r) {
      const int m = m0 + wave * 16 + lgrp * 4 + r;
      C[(size_t)m * DIM_ + n] = acc[nt][r] + bv;
    }
  }
}

// ---------------- depthwise 3x3 conv + bias + SiLU (float4 channels) -------
__global__ __launch_bounds__(256) void conv_silu_k(
    const float* __restrict__ xi, const float* __restrict__ cw,
    const float* __restrict__ cb, float* __restrict__ ca)
{
  const int idx = blockIdx.x * 256 + threadIdx.x;     // over NTOK*192
  if (idx >= NTOK * 192) return;
  const int c4 = (idx % 192) * 4;
  const int t = idx / 192;
  const int s = t & 1023;
  const int y = s >> 5, x = s & 31;
  const int tb = t - s;
  float4 acc = *(const float4*)&cb[c4];
  #pragma unroll
  for (int ky = -1; ky <= 1; ++ky) {
    const int yy = y + ky;
    if (yy < 0 || yy > 31) continue;
    #pragma unroll
    for (int kx = -1; kx <= 1; ++kx) {
      const int xx = x + kx;
      if (xx < 0 || xx > 31) continue;
      const float4 v = *(const float4*)&xi[(size_t)(tb + (yy << 5) + xx) * 1536 + c4];
      const float4 w = *(const float4*)&cw[((ky + 1) * 3 + (kx + 1)) * INNER_ + c4];
      acc.x += v.x * w.x; acc.y += v.y * w.y;
      acc.z += v.z * w.z; acc.w += v.w * w.w;
    }
  }
  float4 o;
  o.x = acc.x / (1.f + __expf(-acc.x));
  o.y = acc.y / (1.f + __expf(-acc.y));
  o.z = acc.z / (1.f + __expf(-acc.z));
  o.w = acc.w / (1.f + __expf(-acc.w));
  *(float4*)&ca[(size_t)t * INNER_ + c4] = o;
}

// ---------------- headwise q,k,v + gate pre-activations --------------------
__global__ __launch_bounds__(256) void headwise_gates_k(
    const float* __restrict__ xi, const float* __restrict__ ca,
    const float* __restrict__ Wq, const float* __restrict__ bq,
    const float* __restrict__ Wk, const float* __restrict__ bk,
    const float* __restrict__ Wv, const float* __restrict__ bv,
    const float* __restrict__ Wig, const float* __restrict__ big,
    const float* __restrict__ Wfg, const float* __restrict__ bfg,
    __hip_bfloat16* __restrict__ qbf, __hip_bfloat16* __restrict__ kbf,
    __hip_bfloat16* __restrict__ vbf,
    float* __restrict__ ig, float* __restrict__ fg)
{
  __shared__ float qs[INNER_], ks[INNER_], vs[INNER_];
  const int t = blockIdx.x;
  const int b = t >> 10, s = t & 1023;
  const int tid = threadIdx.x;
  if (tid < 192) {
    float cav[4], xmv[4];
    #pragma unroll
    for (int d = 0; d < 4; ++d) {
      cav[d] = ca[(size_t)t * INNER_ + tid * 4 + d];
      xmv[d] = xi[(size_t)t * 1536 + tid * 4 + d];
    }
    #pragma unroll
    for (int o = 0; o < 4; ++o) {
      const int cidx = tid * 4 + o;
      float q = bq[cidx], k = bk[cidx], v = bv[cidx];
      #pragma unroll
      for (int d = 0; d < 4; ++d) {
        q += cav[d] * Wq[tid * 16 + o * 4 + d];
        k += cav[d] * Wk[tid * 16 + o * 4 + d];
        v += xmv[d] * Wv[tid * 16 + o * 4 + d];
      }
      qs[cidx] = q; ks[cidx] = k; vs[cidx] = v;
      const int hm = cidx / DH_, dd = cidx % DH_;
      const size_t o2 = ((size_t)(b * NHM_ + hm) * S_ + s) * DH_ + dd;
      qbf[o2] = __float2bfloat16(q);
      kbf[o2] = __float2bfloat16(k);
      vbf[o2] = __float2bfloat16(v);
    }
  }
  __syncthreads();
  const int g = tid >> 5, l32 = tid & 31;
  const float* Wg = (g < 4) ? Wig : Wfg;
  const int h = g & 3;
  float sum = 0.f;
  for (int c = l32; c < INNER_; c += 32) {
    sum += qs[c] * Wg[h * 2304 + c]
         + ks[c] * Wg[h * 2304 + 768 + c]
         + vs[c] * Wg[h * 2304 + 1536 + c];
  }
  #pragma unroll
  for (int m = 16; m >= 1; m >>= 1) sum += __shfl_xor(sum, m);
  if (l32 == 0) {
    if (g < 4) ig[(size_t)(b * NHM_ + h) * S_ + s] = sum + big[h];
    else       fg[(size_t)(b * NHM_ + h) * S_ + s] = sum + bfg[h];
  }
}

// ---------------- V transpose: vtb[bh][d][s] = vbf[bh][s][d] ---------------
__global__ __launch_bounds__(256) void transpose_v_k(
    const __hip_bfloat16* __restrict__ vbf, __hip_bfloat16* __restrict__ vtb)
{
  __shared__ __hip_bfloat16 tile[64][72];
  const int s0 = blockIdx.x * 64, d0 = blockIdx.y * 64, bh = blockIdx.z;
  const int tid = threadIdx.x;
  const int rr = tid >> 3;          // 0..31
  const int cc8 = (tid & 7) * 8;    // 0..56
  #pragma unroll
  for (int it = 0; it < 2; ++it) {
    const int r = rr + it * 32;
    *(bf16x8v*)&tile[r][cc8] =
        *(const bf16x8v*)&vbf[((size_t)bh * S_ + s0 + r) * DH_ + d0 + cc8];
  }
  __syncthreads();
  #pragma unroll
  for (int it = 0; it < 2; ++it) {
    const int r = rr + it * 32;     // d_local
    bf16x8v tmp;
    #pragma unroll
    for (int e = 0; e < 8; ++e) tmp[e] = *(__bf16*)&tile[cc8 + e][r];
    *(bf16x8v*)&vtb[((size_t)bh * DH_ + d0 + r) * S_ + s0 + cc8] = tmp;
  }
}

// ---------------- per-(b,h) scans ------------------------------------------
__global__ __launch_bounds__(64) void gate_scan_k(
    const float* __restrict__ ig, const float* __restrict__ fg,
    float* __restrict__ lfc, float* __restrict__ aa, float* __restrict__ rm)
{
  const int bh = blockIdx.x;
  const int lane = threadIdx.x;
  const float* fgp = fg + bh * S_;
  const float* igp = ig + bh * S_;
  float v[16];
  float run = 0.f;
  #pragma unroll
  for (int i = 0; i < 16; ++i) {
    const float x = fgp[lane * 16 + i];
    const float lf = fminf(x, 0.f) - log1pf(expf(-fabsf(x)));
    run += lf;
    v[i] = run;
  }
  float inc = run;
  #pragma unroll
  for (int off = 1; off < 64; off <<= 1) {
    const float o = __shfl_up(inc, off);
    if (lane >= off) inc += o;
  }
  const float excl = inc - run;
  float rv[16];
  float rmx = -INFINITY;
  #pragma unroll
  for (int i = 0; i < 16; ++i) {
    const float l = v[i] + excl;
    lfc[bh * S_ + lane * 16 + i] = l;
    const float a = igp[lane * 16 + i] - l;
    aa[bh * S_ + lane * 16 + i] = a;
    rmx = fmaxf(rmx, a);
    rv[i] = rmx;
  }
  float incm = rmx;
  #pragma unroll
  for (int off = 1; off < 64; off <<= 1) {
    const float o = __shfl_up(incm, off);
    if (lane >= off) incm = fmaxf(incm, o);
  }
  float exm = __shfl_up(incm, 1);
  if (lane == 0) exm = -INFINITY;
  #pragma unroll
  for (int i = 0; i < 16; ++i) {
    rm[bh * S_ + lane * 16 + i] = fmaxf(rv[i], exm);
  }
}

// ---------------- mLSTM attention: partial kernel --------------------------
// pacc layout: [((bh*SLOTS+slot)*16 + wave*4 + lgrp)*12 + dd]*64 + lrow*4 (+r)
__global__ __launch_bounds__(256) void mlstm_part_k(
    const __hip_bfloat16* __restrict__ qbf, const __hip_bfloat16* __restrict__ kbf,
    const __hip_bfloat16* __restrict__ vtb,
    const float* __restrict__ aa, const float* __restrict__ rm,
    float* __restrict__ pacc, float* __restrict__ rsp)
{
  __shared__ __hip_bfloat16 Pl[4][16][40];
  const int bh = blockIdx.y;
  const int slot = blockIdx.x;
  int t = 0, base = 0;
  #pragma unroll
  for (int s = 0; s < 16; ++s) {
    const int sz = (s >> 2) + 1;
    if (slot >= base + sz) { base += sz; t = s + 1; }
  }
  const int c = slot - base;
  const int jt_lo = c * 8;
  const int jt_hi = min(jt_lo + 8, 2 * t + 2);

  const int wave = threadIdx.x >> 6, lane = threadIdx.x & 63;
  const int lrow = lane & 15, lgrp = lane >> 4;
  const int q0 = t * 64 + wave * 16;
  const __hip_bfloat16* Q  = qbf + (size_t)bh * S_ * DH_;
  const __hip_bfloat16* Kp = kbf + (size_t)bh * S_ * DH_;
  const __hip_bfloat16* VT = vtb + (size_t)bh * DH_ * S_;
  const float* aap = aa + bh * S_;
  const float* rmp = rm + bh * S_;

  bf16x8v qf[6];
  #pragma unroll
  for (int kk = 0; kk < 6; ++kk)
    qf[kk] = *(const bf16x8v*)&Q[(size_t)(q0 + lrow) * DH_ + kk * 32 + lgrp * 8];
  float rmi[4];
  #pragma unroll
  for (int r = 0; r < 4; ++r) rmi[r] = rmp[q0 + lgrp * 4 + r];

  const f32x4 zero4 = {0.f, 0.f, 0.f, 0.f};
  f32x4 hacc[12];
  #pragma unroll
  for (int dd = 0; dd < 12; ++dd) hacc[dd] = zero4;
  float rs[4] = {0.f, 0.f, 0.f, 0.f};
  const float scale = 0.07216878364870323f;   // 1/sqrt(192)
  const int myqmax = q0 + 15;

  for (int jt = jt_lo; jt < jt_hi; ++jt) {
    const int j0 = jt * 32;
    if (j0 > myqmax) break;            // past this wave's causal frontier
    f32x4 sacc[2];
    sacc[0] = zero4; sacc[1] = zero4;
    #pragma unroll
    for (int jj = 0; jj < 2; ++jj) {
      #pragma unroll
      for (int kk = 0; kk < 6; ++kk) {
        const bf16x8v kf = *(const bf16x8v*)
            &Kp[(size_t)(j0 + jj * 16 + lrow) * DH_ + kk * 32 + lgrp * 8];
        sacc[jj] = mfma16(qf[kk], kf, sacc[jj]);
      }
    }
    #pragma unroll
    for (int jj = 0; jj < 2; ++jj) {
      const int j = j0 + jj * 16 + lrow;
      const float aj = aap[j];
      #pragma unroll
      for (int r = 0; r < 4; ++r) {
        const int i_ = q0 + lgrp * 4 + r;
        float cval = 0.f;
        if (j <= i_) cval = sacc[jj][r] * scale * __expf(aj - rmi[r]);
        rs[r] += cval;
        Pl[wave][lgrp * 4 + r][jj * 16 + lrow] = __float2bfloat16(cval);
      }
    }
    // per-wave LDS round-trip; compiler inserts lgkmcnt ordering (no barrier)
    const bf16x8v pf = *(const bf16x8v*)&Pl[wave][lrow][lgrp * 8];
    #pragma unroll
    for (int dd = 0; dd < 12; ++dd) {
      const bf16x8v vf = *(const bf16x8v*)
          &VT[(size_t)(dd * 16 + lrow) * S_ + j0 + lgrp * 8];
      hacc[dd] = mfma16(pf, vf, hacc[dd]);
    }
  }

  #pragma unroll
  for (int r = 0; r < 4; ++r) {
    #pragma unroll
    for (int m = 1; m < 16; m <<= 1) rs[r] += __shfl_xor(rs[r], m);
  }
  const size_t pb16 = ((size_t)bh * SLOTS_ + slot) * 16 + wave * 4 + lgrp;
  #pragma unroll
  for (int dd = 0; dd < 12; ++dd) {
    *(f32x4*)&pacc[(pb16 * 12 + dd) * 64 + lrow * 4] = hacc[dd];
  }
  if (lrow == 0) {
    #pragma unroll
    for (int r = 0; r < 4; ++r)
      rsp[((size_t)bh * SLOTS_ + slot) * 64 + wave * 16 + lgrp * 4 + r] = rs[r];
  }
}

// ---------------- mLSTM reduce + fused epilogue (bf16 h_state out) ---------
__global__ __launch_bounds__(256) void mlstm_red_k(
    const float* __restrict__ pacc, const float* __restrict__ rsp,
    const float* __restrict__ lfc, const float* __restrict__ rm,
    const float* __restrict__ ca, const float* __restrict__ xi,
    const float* __restrict__ nw, const float* __restrict__ nb,
    const float* __restrict__ skip, __hip_bfloat16* __restrict__ hs)
{
  const int t = blockIdx.x, bh = blockIdx.y;
  const int b = bh >> 2, hm = bh & 3;
  int base = 0;
  #pragma unroll
  for (int s = 0; s < 16; ++s) if (s < t) base += (s >> 2) + 1;
  const int nc = (t >> 2) + 1;

  const int wave = threadIdx.x >> 6, lane = threadIdx.x & 63;
  const int lrow = lane & 15, lgrp = lane >> 4;
  const int q0 = t * 64 + wave * 16;
  const float* lfcp = lfc + bh * S_;
  const float* rmp  = rm + bh * S_;

  f32x4 hsum[12];
  #pragma unroll
  for (int dd = 0; dd < 12; ++dd) hsum[dd] = f32x4{0.f, 0.f, 0.f, 0.f};
  float rst[4] = {0.f, 0.f, 0.f, 0.f};

  for (int cc = 0; cc < nc; ++cc) {
    const size_t pb16 = ((size_t)bh * SLOTS_ + base + cc) * 16 + wave * 4 + lgrp;
    #pragma unroll
    for (int dd = 0; dd < 12; ++dd) {
      const f32x4 p = *(const f32x4*)&pacc[(pb16 * 12 + dd) * 64 + lrow * 4];
      hsum[dd] += p;
    }
    #pragma unroll
    for (int r = 0; r < 4; ++r)
      rst[r] += rsp[((size_t)bh * SLOTS_ + base + cc) * 64 + wave * 16 + lgrp * 4 + r];
  }

  #pragma unroll
  for (int r = 0; r < 4; ++r) {
    const int i_ = q0 + lgrp * 4 + r;
    const int tok = b * S_ + i_;
    const float mld = lfcp[i_] + rmp[i_];
    const float nrm = fmaxf(fabsf(rst[r]), __expf(-mld)) + 1e-6f;
    float hv[12];
    float sum = 0.f, sq = 0.f;
    #pragma unroll
    for (int dd = 0; dd < 12; ++dd) {
      const float x = hsum[dd][r] / nrm;
      hv[dd] = x; sum += x; sq += x * x;
    }
    #pragma unroll
    for (int m = 1; m < 16; m <<= 1) {
      sum += __shfl_xor(sum, m);
      sq  += __shfl_xor(sq, m);
    }
    const float mean = sum * (1.f / 192.f);
    const float var  = sq * (1.f / 192.f) - mean * mean;
    const float rstd = rsqrtf(var + 1e-5f);
    #pragma unroll
    for (int dd = 0; dd < 12; ++dd) {
      const int cidx = hm * DH_ + dd * 16 + lrow;
      const float hn = (hv[dd] - mean) * rstd * nw[cidx] + nb[cidx];
      const float cav = ca[(size_t)tok * INNER_ + cidx];
      const float zz  = xi[(size_t)tok * 1536 + 768 + cidx];
      const float hsv = (hn + skip[cidx] * cav) * (zz / (1.f + __expf(-zz)));
      hs[(size_t)tok * INNER_ + cidx] = __float2bfloat16(hsv);
    }
  }
}

// ---------------------------------------------------------------------------
extern "C" void kernel_launch(void* const* d_in, const int* in_sizes, int n_in,
                              void* d_out, int out_size, void* d_ws, size_t ws_size,
                              hipStream_t stream) {
  const float* x      = (const float*)d_in[0];
  const float* W_up   = (const float*)d_in[1];
  const float* b_up   = (const float*)d_in[2];
  const float* Wq     = (const float*)d_in[3];
  const float* bq     = (const float*)d_in[4];
  const float* Wk     = (const float*)d_in[5];
  const float* bk     = (const float*)d_in[6];
  const float* Wv     = (const float*)d_in[7];
  const float* bv     = (const float*)d_in[8];
  const float* conv_w = (const float*)d_in[9];
  const float* conv_b = (const float*)d_in[10];
  const float* W_ig   = (const float*)d_in[11];
  const float* b_ig   = (const float*)d_in[12];
  const float* W_fg   = (const float*)d_in[13];
  const float* b_fg   = (const float*)d_in[14];
  const float* norm_w = (const float*)d_in[15];
  const float* norm_b = (const float*)d_in[16];
  const float* skip   = (const float*)d_in[17];
  const float* W_down = (const float*)d_in[18];
  const float* b_down = (const float*)d_in[19];
  float* out = (float*)d_out;

  char* ws = (char*)d_ws;
  constexpr size_t OFF_XI  = 0;
  constexpr size_t OFF_CA  = OFF_XI + (size_t)NTOK * 1536 * 4;
  constexpr size_t OFF_QBF = OFF_CA + (size_t)NTOK * INNER_ * 4;
  constexpr size_t OFF_KBF = OFF_QBF + (size_t)16 * S_ * DH_ * 2;
  constexpr size_t OFF_VBF = OFF_KBF + (size_t)16 * S_ * DH_ * 2;
  constexpr size_t OFF_IG  = OFF_VBF + (size_t)16 * S_ * DH_ * 2;
  constexpr size_t OFF_FG  = OFF_IG + (size_t)16 * S_ * 4;
  constexpr size_t OFF_LFC = OFF_FG + (size_t)16 * S_ * 4;
  constexpr size_t OFF_AA  = OFF_LFC + (size_t)16 * S_ * 4;
  constexpr size_t OFF_RM  = OFF_AA + (size_t)16 * S_ * 4;
  constexpr size_t OFF_HS  = OFF_RM + (size_t)16 * S_ * 4;
  constexpr size_t OFF_XB  = OFF_HS + (size_t)NTOK * INNER_ * 4;
  constexpr size_t OFF_WUB = OFF_XB + (size_t)NTOK * DIM_ * 2;
  constexpr size_t OFF_PAC = OFF_WUB + (size_t)1536 * DIM_ * 2;
  constexpr size_t OFF_RSP = OFF_PAC + (size_t)16 * SLOTS_ * 64 * 192 * 4;
  constexpr size_t OFF_WDB = OFF_RSP + (size_t)16 * SLOTS_ * 64 * 4;
  constexpr size_t OFF_VTB = OFF_WDB + (size_t)DIM_ * INNER_ * 2;

  float* x_inner = (float*)(ws + OFF_XI);
  float* conv_a  = (float*)(ws + OFF_CA);
  __hip_bfloat16* qbf = (__hip_bfloat16*)(ws + OFF_QBF);
  __hip_bfloat16* kbf = (__hip_bfloat16*)(ws + OFF_KBF);
  __hip_bfloat16* vbf = (__hip_bfloat16*)(ws + OFF_VBF);
  float* ig  = (float*)(ws + OFF_IG);
  float* fg  = (float*)(ws + OFF_FG);
  float* lfc = (float*)(ws + OFF_LFC);
  float* aav = (float*)(ws + OFF_AA);
  float* rmv = (float*)(ws + OFF_RM);
  __hip_bfloat16* hsb = (__hip_bfloat16*)(ws + OFF_HS);
  __hip_bfloat16* xb  = (__hip_bfloat16*)(ws + OFF_XB);
  __hip_bfloat16* wub = (__hip_bfloat16*)(ws + OFF_WUB);
  float* pacc = (float*)(ws + OFF_PAC);
  float* rsp  = (float*)(ws + OFF_RSP);
  __hip_bfloat16* wdb = (__hip_bfloat16*)(ws + OFF_WDB);
  __hip_bfloat16* vtb = (__hip_bfloat16*)(ws + OFF_VTB);

  // 0) casts
  cast_bf16_k<<<(NTOK * DIM_ / 4 + 255) / 256, 256, 0, stream>>>(x, xb, NTOK * DIM_ / 4);
  cast_bf16_k<<<(1536 * DIM_ / 4 + 255) / 256, 256, 0, stream>>>(W_up, wub, 1536 * DIM_ / 4);
  cast_bf16_k<<<(DIM_ * INNER_ / 4 + 255) / 256, 256, 0, stream>>>(W_down, wdb, DIM_ * INNER_ / 4);
  // 1) up-projection (bf16 MFMA)
  gemm_up_k<<<dim3(12, 64), 256, 0, stream>>>(xb, wub, b_up, x_inner);
  // 2) depthwise conv + SiLU
  conv_silu_k<<<(NTOK * 192) / 256, 256, 0, stream>>>(x_inner, conv_w, conv_b, conv_a);
  // 3) headwise q,k,v + gates
  headwise_gates_k<<<NTOK, 256, 0, stream>>>(
      x_inner, conv_a, Wq, bq, Wk, bk, Wv, bv, W_ig, b_ig, W_fg, b_fg,
      qbf, kbf, vbf, ig, fg);
  // 3b) V transpose
  transpose_v_k<<<dim3(16, 3, 16), 256, 0, stream>>>(vbf, vtb);
  // 4) gate scans
  gate_scan_k<<<16, 64, 0, stream>>>(ig, fg, lfc, aav, rmv);
  // 5a) attention partials
  mlstm_part_k<<<dim3(SLOTS_, 16), 256, 0, stream>>>(qbf, kbf, vtb, aav, rmv, pacc, rsp);
  // 5b) reduce + epilogue
  mlstm_red_k<<<dim3(16, 16), 256, 0, stream>>>(
      pacc, rsp, lfc, rmv, conv_a, x_inner, norm_w, norm_b, skip, hsb);
  // 6) down-projection (bf16 MFMA, fp32 out)
  gemm_down_k<<<dim3(3, 64), 256, 0, stream>>>(hsb, wdb, b_down, out);
}

// Round 6
// 205.177 us; speedup vs baseline: 1.1740x; 1.1740x over previous
//
#include <hip/hip_runtime.h>
#include <hip/hip_bf16.h>

// ---------------------------------------------------------------------------
// ViLLayer forward, round 5:
//   mlstm_part_k rebuilt: cooperative double-buffered LDS staging of the
//   shared K-tile and V^T-tile (reg-staged T14 async split: issue-early /
//   ds_write-late), fragment-ordered LDS layouts (conflict-free b128 reads),
//   one barrier per j-tile. Decouples the per-MFMA global-latency chain
//   that bounded R4.
// ---------------------------------------------------------------------------

#define B_     4
#define S_     1024
#define DIM_   384
#define INNER_ 768
#define NHM_   4
#define DH_    192
#define NTOK   (B_*S_)      // 4096
#define SLOTS_ 40           // sum over t of ceil((t+1)/4)

typedef __attribute__((ext_vector_type(8))) __bf16 bf16x8v;
typedef __attribute__((ext_vector_type(4))) float  f32x4;

static __device__ __forceinline__ f32x4 mfma16(bf16x8v a, bf16x8v b, f32x4 c) {
  return __builtin_amdgcn_mfma_f32_16x16x32_bf16(a, b, c, 0, 0, 0);
}

// ---------------- cast fp32 -> bf16 (vectorized) ---------------------------
__global__ __launch_bounds__(256) void cast_bf16_k(
    const float* __restrict__ in, __hip_bfloat16* __restrict__ out, int n4)
{
  const int i = blockIdx.x * 256 + threadIdx.x;
  if (i >= n4) return;
  const float4 v = *(const float4*)&in[i * 4];
  out[i * 4 + 0] = __float2bfloat16(v.x);
  out[i * 4 + 1] = __float2bfloat16(v.y);
  out[i * 4 + 2] = __float2bfloat16(v.z);
  out[i * 4 + 3] = __float2bfloat16(v.w);
}

// ---------------- up-proj: bf16 MFMA GEMM ----------------------------------
__global__ __launch_bounds__(256) void gemm_up_k(
    const __hip_bfloat16* __restrict__ xb, const __hip_bfloat16* __restrict__ Wb,
    const float* __restrict__ bias, float* __restrict__ C)
{
  const int n0 = blockIdx.x * 128, m0 = blockIdx.y * 64;
  const int wave = threadIdx.x >> 6, lane = threadIdx.x & 63;
  const int lrow = lane & 15, lgrp = lane >> 4;
  const __hip_bfloat16* xr = xb + (size_t)(m0 + wave * 16 + lrow) * DIM_;
  f32x4 acc[8];
  #pragma unroll
  for (int nt = 0; nt < 8; ++nt) acc[nt] = f32x4{0.f, 0.f, 0.f, 0.f};
  for (int k0 = 0; k0 < DIM_; k0 += 32) {
    const bf16x8v af = *(const bf16x8v*)&xr[k0 + lgrp * 8];
    #pragma unroll
    for (int nt = 0; nt < 8; ++nt) {
      const bf16x8v bf = *(const bf16x8v*)
          &Wb[(size_t)(n0 + nt * 16 + lrow) * DIM_ + k0 + lgrp * 8];
      acc[nt] = mfma16(af, bf, acc[nt]);
    }
  }
  #pragma unroll
  for (int nt = 0; nt < 8; ++nt) {
    const int n = n0 + nt * 16 + lrow;
    const float bv = bias[n];
    #pragma unroll
    for (int r = 0; r < 4; ++r) {
      const int m = m0 + wave * 16 + lgrp * 4 + r;
      C[(size_t)m * 1536 + n] = acc[nt][r] + bv;
    }
  }
}

// ---------------- down-proj: bf16 MFMA GEMM --------------------------------
__global__ __launch_bounds__(256) void gemm_down_k(
    const __hip_bfloat16* __restrict__ hsb, const __hip_bfloat16* __restrict__ Wdb,
    const float* __restrict__ bias, float* __restrict__ C)
{
  const int n0 = blockIdx.x * 128, m0 = blockIdx.y * 64;
  const int wave = threadIdx.x >> 6, lane = threadIdx.x & 63;
  const int lrow = lane & 15, lgrp = lane >> 4;
  const __hip_bfloat16* ar = hsb + (size_t)(m0 + wave * 16 + lrow) * INNER_;
  f32x4 acc[8];
  #pragma unroll
  for (int nt = 0; nt < 8; ++nt) acc[nt] = f32x4{0.f, 0.f, 0.f, 0.f};
  for (int k0 = 0; k0 < INNER_; k0 += 32) {
    const bf16x8v af = *(const bf16x8v*)&ar[k0 + lgrp * 8];
    #pragma unroll
    for (int nt = 0; nt < 8; ++nt) {
      const bf16x8v bf = *(const bf16x8v*)
          &Wdb[(size_t)(n0 + nt * 16 + lrow) * INNER_ + k0 + lgrp * 8];
      acc[nt] = mfma16(af, bf, acc[nt]);
    }
  }
  #pragma unroll
  for (int nt = 0; nt < 8; ++nt) {
    const int n = n0 + nt * 16 + lrow;
    const float bv = bias[n];
    #pragma unroll
    for (int r = 0; r < 4; ++r) {
      const int m = m0 + wave * 16 + lgrp * 4 + r;
      C[(size_t)m * DIM_ + n] = acc[nt][r] + bv;
    }
  }
}

// ---------------- depthwise 3x3 conv + bias + SiLU (float4 channels) -------
__global__ __launch_bounds__(256) void conv_silu_k(
    const float* __restrict__ xi, const float* __restrict__ cw,
    const float* __restrict__ cb, float* __restrict__ ca)
{
  const int idx = blockIdx.x * 256 + threadIdx.x;     // over NTOK*192
  if (idx >= NTOK * 192) return;
  const int c4 = (idx % 192) * 4;
  const int t = idx / 192;
  const int s = t & 1023;
  const int y = s >> 5, x = s & 31;
  const int tb = t - s;
  float4 acc = *(const float4*)&cb[c4];
  #pragma unroll
  for (int ky = -1; ky <= 1; ++ky) {
    const int yy = y + ky;
    if (yy < 0 || yy > 31) continue;
    #pragma unroll
    for (int kx = -1; kx <= 1; ++kx) {
      const int xx = x + kx;
      if (xx < 0 || xx > 31) continue;
      const float4 v = *(const float4*)&xi[(size_t)(tb + (yy << 5) + xx) * 1536 + c4];
      const float4 w = *(const float4*)&cw[((ky + 1) * 3 + (kx + 1)) * INNER_ + c4];
      acc.x += v.x * w.x; acc.y += v.y * w.y;
      acc.z += v.z * w.z; acc.w += v.w * w.w;
    }
  }
  float4 o;
  o.x = acc.x / (1.f + __expf(-acc.x));
  o.y = acc.y / (1.f + __expf(-acc.y));
  o.z = acc.z / (1.f + __expf(-acc.z));
  o.w = acc.w / (1.f + __expf(-acc.w));
  *(float4*)&ca[(size_t)t * INNER_ + c4] = o;
}

// ---------------- headwise q,k,v + gate pre-activations --------------------
__global__ __launch_bounds__(256) void headwise_gates_k(
    const float* __restrict__ xi, const float* __restrict__ ca,
    const float* __restrict__ Wq, const float* __restrict__ bq,
    const float* __restrict__ Wk, const float* __restrict__ bk,
    const float* __restrict__ Wv, const float* __restrict__ bv,
    const float* __restrict__ Wig, const float* __restrict__ big,
    const float* __restrict__ Wfg, const float* __restrict__ bfg,
    __hip_bfloat16* __restrict__ qbf, __hip_bfloat16* __restrict__ kbf,
    __hip_bfloat16* __restrict__ vbf,
    float* __restrict__ ig, float* __restrict__ fg)
{
  __shared__ float qs[INNER_], ks[INNER_], vs[INNER_];
  const int t = blockIdx.x;
  const int b = t >> 10, s = t & 1023;
  const int tid = threadIdx.x;
  if (tid < 192) {
    float cav[4], xmv[4];
    #pragma unroll
    for (int d = 0; d < 4; ++d) {
      cav[d] = ca[(size_t)t * INNER_ + tid * 4 + d];
      xmv[d] = xi[(size_t)t * 1536 + tid * 4 + d];
    }
    #pragma unroll
    for (int o = 0; o < 4; ++o) {
      const int cidx = tid * 4 + o;
      float q = bq[cidx], k = bk[cidx], v = bv[cidx];
      #pragma unroll
      for (int d = 0; d < 4; ++d) {
        q += cav[d] * Wq[tid * 16 + o * 4 + d];
        k += cav[d] * Wk[tid * 16 + o * 4 + d];
        v += xmv[d] * Wv[tid * 16 + o * 4 + d];
      }
      qs[cidx] = q; ks[cidx] = k; vs[cidx] = v;
      const int hm = cidx / DH_, dd = cidx % DH_;
      const size_t o2 = ((size_t)(b * NHM_ + hm) * S_ + s) * DH_ + dd;
      qbf[o2] = __float2bfloat16(q);
      kbf[o2] = __float2bfloat16(k);
      vbf[o2] = __float2bfloat16(v);
    }
  }
  __syncthreads();
  const int g = tid >> 5, l32 = tid & 31;
  const float* Wg = (g < 4) ? Wig : Wfg;
  const int h = g & 3;
  float sum = 0.f;
  for (int c = l32; c < INNER_; c += 32) {
    sum += qs[c] * Wg[h * 2304 + c]
         + ks[c] * Wg[h * 2304 + 768 + c]
         + vs[c] * Wg[h * 2304 + 1536 + c];
  }
  #pragma unroll
  for (int m = 16; m >= 1; m >>= 1) sum += __shfl_xor(sum, m);
  if (l32 == 0) {
    if (g < 4) ig[(size_t)(b * NHM_ + h) * S_ + s] = sum + big[h];
    else       fg[(size_t)(b * NHM_ + h) * S_ + s] = sum + bfg[h];
  }
}

// ---------------- V transpose: vtb[bh][d][s] = vbf[bh][s][d] ---------------
__global__ __launch_bounds__(256) void transpose_v_k(
    const __hip_bfloat16* __restrict__ vbf, __hip_bfloat16* __restrict__ vtb)
{
  __shared__ __hip_bfloat16 tile[64][72];
  const int s0 = blockIdx.x * 64, d0 = blockIdx.y * 64, bh = blockIdx.z;
  const int tid = threadIdx.x;
  const int rr = tid >> 3;          // 0..31
  const int cc8 = (tid & 7) * 8;    // 0..56
  #pragma unroll
  for (int it = 0; it < 2; ++it) {
    const int r = rr + it * 32;
    *(bf16x8v*)&tile[r][cc8] =
        *(const bf16x8v*)&vbf[((size_t)bh * S_ + s0 + r) * DH_ + d0 + cc8];
  }
  __syncthreads();
  #pragma unroll
  for (int it = 0; it < 2; ++it) {
    const int r = rr + it * 32;     // d_local
    bf16x8v tmp;
    #pragma unroll
    for (int e = 0; e < 8; ++e) tmp[e] = *(__bf16*)&tile[cc8 + e][r];
    *(bf16x8v*)&vtb[((size_t)bh * DH_ + d0 + r) * S_ + s0 + cc8] = tmp;
  }
}

// ---------------- per-(b,h) scans ------------------------------------------
__global__ __launch_bounds__(64) void gate_scan_k(
    const float* __restrict__ ig, const float* __restrict__ fg,
    float* __restrict__ lfc, float* __restrict__ aa, float* __restrict__ rm)
{
  const int bh = blockIdx.x;
  const int lane = threadIdx.x;
  const float* fgp = fg + bh * S_;
  const float* igp = ig + bh * S_;
  float v[16];
  float run = 0.f;
  #pragma unroll
  for (int i = 0; i < 16; ++i) {
    const float x = fgp[lane * 16 + i];
    const float lf = fminf(x, 0.f) - log1pf(expf(-fabsf(x)));
    run += lf;
    v[i] = run;
  }
  float inc = run;
  #pragma unroll
  for (int off = 1; off < 64; off <<= 1) {
    const float o = __shfl_up(inc, off);
    if (lane >= off) inc += o;
  }
  const float excl = inc - run;
  float rv[16];
  float rmx = -INFINITY;
  #pragma unroll
  for (int i = 0; i < 16; ++i) {
    const float l = v[i] + excl;
    lfc[bh * S_ + lane * 16 + i] = l;
    const float a = igp[lane * 16 + i] - l;
    aa[bh * S_ + lane * 16 + i] = a;
    rmx = fmaxf(rmx, a);
    rv[i] = rmx;
  }
  float incm = rmx;
  #pragma unroll
  for (int off = 1; off < 64; off <<= 1) {
    const float o = __shfl_up(incm, off);
    if (lane >= off) incm = fmaxf(incm, o);
  }
  float exm = __shfl_up(incm, 1);
  if (lane == 0) exm = -INFINITY;
  #pragma unroll
  for (int i = 0; i < 16; ++i) {
    rm[bh * S_ + lane * 16 + i] = fmaxf(rv[i], exm);
  }
}

// ---------------- mLSTM attention: partial kernel --------------------------
// grid (SLOTS_, 16 bh), 256 thr = 4 waves. Double-buffered LDS staging of
// the shared K-tile (32 j x 192 d) and VT-tile (192 d x 32 j) per j-tile.
// LDS layouts are fragment-ordered 16B slots:
//   K:  slot = kk*128 + j*4 + g   (g = 8-elem chunk within 32-elem k-step)
//   VT: slot = d*4 + g            (g = 8-col chunk of the 64B row segment)
// so staging writes are lane-consecutive and all ds_read_b128 are
// 64-consecutive-slot (conflict-free).
__global__ __launch_bounds__(256) void mlstm_part_k(
    const __hip_bfloat16* __restrict__ qbf, const __hip_bfloat16* __restrict__ kbf,
    const __hip_bfloat16* __restrict__ vtb,
    const float* __restrict__ aa, const float* __restrict__ rm,
    float* __restrict__ pacc, float* __restrict__ rsp)
{
  __shared__ __hip_bfloat16 Kl[2][6144];
  __shared__ __hip_bfloat16 Vl[2][6144];
  __shared__ __hip_bfloat16 Pl[4][16][40];
  const int bh = blockIdx.y;
  const int slot = blockIdx.x;
  int t = 0, base = 0;
  #pragma unroll
  for (int s = 0; s < 16; ++s) {
    const int sz = (s >> 2) + 1;
    if (slot >= base + sz) { base += sz; t = s + 1; }
  }
  const int c = slot - base;
  const int jt_lo = c * 8;
  const int jt_hi = min(jt_lo + 8, 2 * t + 2);

  const int wave = threadIdx.x >> 6, lane = threadIdx.x & 63;
  const int lrow = lane & 15, lgrp = lane >> 4;
  const int q0 = t * 64 + wave * 16;
  const __hip_bfloat16* Q  = qbf + (size_t)bh * S_ * DH_;
  const __hip_bfloat16* Kp = kbf + (size_t)bh * S_ * DH_;
  const __hip_bfloat16* VT = vtb + (size_t)bh * DH_ * S_;
  const float* aap = aa + bh * S_;
  const float* rmp = rm + bh * S_;

  bf16x8v qf[6];
  #pragma unroll
  for (int kk = 0; kk < 6; ++kk)
    qf[kk] = *(const bf16x8v*)&Q[(size_t)(q0 + lrow) * DH_ + kk * 32 + lgrp * 8];
  float rmi[4];
  #pragma unroll
  for (int r = 0; r < 4; ++r) rmi[r] = rmp[q0 + lgrp * 4 + r];

  const f32x4 zero4 = {0.f, 0.f, 0.f, 0.f};
  f32x4 hacc[12];
  #pragma unroll
  for (int dd = 0; dd < 12; ++dd) hacc[dd] = zero4;
  float rs[4] = {0.f, 0.f, 0.f, 0.f};
  const float scale = 0.07216878364870323f;   // 1/sqrt(192)
  const int myqmax = q0 + 15;

  // per-thread staging registers (3 K-slots + 3 V-slots of 16B)
  bf16x8v kreg[3], vreg[3];
  const int s0_ = wave * 192 + lane;           // slot of chunk i: s0_ + i*64

  auto stage_load = [&](int j0s) {
    #pragma unroll
    for (int i = 0; i < 3; ++i) {
      const int s = s0_ + i * 64;
      const int kk = s >> 7, jr = (s >> 2) & 31, g = s & 3;
      kreg[i] = *(const bf16x8v*)&Kp[(size_t)(j0s + jr) * DH_ + kk * 32 + g * 8];
      const int d = s >> 2;                    // 0..191
      vreg[i] = *(const bf16x8v*)&VT[(size_t)d * S_ + j0s + g * 8];
    }
  };
  auto stage_write = [&](int buf) {
    #pragma unroll
    for (int i = 0; i < 3; ++i) {
      const int s = s0_ + i * 64;
      *(bf16x8v*)&Kl[buf][s << 3] = kreg[i];
      *(bf16x8v*)&Vl[buf][s << 3] = vreg[i];
    }
  };

  stage_load(jt_lo * 32);
  stage_write(0);
  __syncthreads();
  int cur = 0;

  for (int jt = jt_lo; jt < jt_hi; ++jt) {
    const int j0 = jt * 32;
    const bool nxt = (jt + 1 < jt_hi);
    if (nxt) stage_load((jt + 1) * 32);        // issue early (T14)
    if (j0 <= myqmax) {
      f32x4 sacc[2];
      sacc[0] = zero4; sacc[1] = zero4;
      #pragma unroll
      for (int jj = 0; jj < 2; ++jj) {
        #pragma unroll
        for (int kk = 0; kk < 6; ++kk) {
          const bf16x8v kf = *(const bf16x8v*)
              &Kl[cur][(kk * 128 + (jj * 16 + lrow) * 4 + lgrp) << 3];
          sacc[jj] = mfma16(qf[kk], kf, sacc[jj]);
        }
      }
      #pragma unroll
      for (int jj = 0; jj < 2; ++jj) {
        const int j = j0 + jj * 16 + lrow;
        const float ajv = aap[j];
        #pragma unroll
        for (int r = 0; r < 4; ++r) {
          const int i_ = q0 + lgrp * 4 + r;
          float cval = 0.f;
          if (j <= i_) cval = sacc[jj][r] * scale * __expf(ajv - rmi[r]);
          rs[r] += cval;
          Pl[wave][lgrp * 4 + r][jj * 16 + lrow] = __float2bfloat16(cval);
        }
      }
      const bf16x8v pf = *(const bf16x8v*)&Pl[wave][lrow][lgrp * 8];
      #pragma unroll
      for (int dd = 0; dd < 12; ++dd) {
        const bf16x8v vf = *(const bf16x8v*)
            &Vl[cur][(dd * 64 + lrow * 4 + lgrp) << 3];
        hacc[dd] = mfma16(pf, vf, hacc[dd]);
      }
    }
    if (nxt) stage_write(cur ^ 1);             // write late, after compute
    __syncthreads();
    cur ^= 1;
  }

  #pragma unroll
  for (int r = 0; r < 4; ++r) {
    #pragma unroll
    for (int m = 1; m < 16; m <<= 1) rs[r] += __shfl_xor(rs[r], m);
  }
  const size_t pb16 = ((size_t)bh * SLOTS_ + slot) * 16 + wave * 4 + lgrp;
  #pragma unroll
  for (int dd = 0; dd < 12; ++dd) {
    *(f32x4*)&pacc[(pb16 * 12 + dd) * 64 + lrow * 4] = hacc[dd];
  }
  if (lrow == 0) {
    #pragma unroll
    for (int r = 0; r < 4; ++r)
      rsp[((size_t)bh * SLOTS_ + slot) * 64 + wave * 16 + lgrp * 4 + r] = rs[r];
  }
}

// ---------------- mLSTM reduce + fused epilogue (bf16 h_state out) ---------
__global__ __launch_bounds__(256) void mlstm_red_k(
    const float* __restrict__ pacc, const float* __restrict__ rsp,
    const float* __restrict__ lfc, const float* __restrict__ rm,
    const float* __restrict__ ca, const float* __restrict__ xi,
    const float* __restrict__ nw, const float* __restrict__ nb,
    const float* __restrict__ skip, __hip_bfloat16* __restrict__ hs)
{
  const int t = blockIdx.x, bh = blockIdx.y;
  const int b = bh >> 2, hm = bh & 3;
  int base = 0;
  #pragma unroll
  for (int s = 0; s < 16; ++s) if (s < t) base += (s >> 2) + 1;
  const int nc = (t >> 2) + 1;

  const int wave = threadIdx.x >> 6, lane = threadIdx.x & 63;
  const int lrow = lane & 15, lgrp = lane >> 4;
  const int q0 = t * 64 + wave * 16;
  const float* lfcp = lfc + bh * S_;
  const float* rmp  = rm + bh * S_;

  f32x4 hsum[12];
  #pragma unroll
  for (int dd = 0; dd < 12; ++dd) hsum[dd] = f32x4{0.f, 0.f, 0.f, 0.f};
  float rst[4] = {0.f, 0.f, 0.f, 0.f};

  for (int cc = 0; cc < nc; ++cc) {
    const size_t pb16 = ((size_t)bh * SLOTS_ + base + cc) * 16 + wave * 4 + lgrp;
    #pragma unroll
    for (int dd = 0; dd < 12; ++dd) {
      const f32x4 p = *(const f32x4*)&pacc[(pb16 * 12 + dd) * 64 + lrow * 4];
      hsum[dd] += p;
    }
    #pragma unroll
    for (int r = 0; r < 4; ++r)
      rst[r] += rsp[((size_t)bh * SLOTS_ + base + cc) * 64 + wave * 16 + lgrp * 4 + r];
  }

  #pragma unroll
  for (int r = 0; r < 4; ++r) {
    const int i_ = q0 + lgrp * 4 + r;
    const int tok = b * S_ + i_;
    const float mld = lfcp[i_] + rmp[i_];
    const float nrm = fmaxf(fabsf(rst[r]), __expf(-mld)) + 1e-6f;
    float hv[12];
    float sum = 0.f, sq = 0.f;
    #pragma unroll
    for (int dd = 0; dd < 12; ++dd) {
      const float x = hsum[dd][r] / nrm;
      hv[dd] = x; sum += x; sq += x * x;
    }
    #pragma unroll
    for (int m = 1; m < 16; m <<= 1) {
      sum += __shfl_xor(sum, m);
      sq  += __shfl_xor(sq, m);
    }
    const float mean = sum * (1.f / 192.f);
    const float var  = sq * (1.f / 192.f) - mean * mean;
    const float rstd = rsqrtf(var + 1e-5f);
    #pragma unroll
    for (int dd = 0; dd < 12; ++dd) {
      const int cidx = hm * DH_ + dd * 16 + lrow;
      const float hn = (hv[dd] - mean) * rstd * nw[cidx] + nb[cidx];
      const float cav = ca[(size_t)tok * INNER_ + cidx];
      const float zz  = xi[(size_t)tok * 1536 + 768 + cidx];
      const float hsv = (hn + skip[cidx] * cav) * (zz / (1.f + __expf(-zz)));
      hs[(size_t)tok * INNER_ + cidx] = __float2bfloat16(hsv);
    }
  }
}

// ---------------------------------------------------------------------------
extern "C" void kernel_launch(void* const* d_in, const int* in_sizes, int n_in,
                              void* d_out, int out_size, void* d_ws, size_t ws_size,
                              hipStream_t stream) {
  const float* x      = (const float*)d_in[0];
  const float* W_up   = (const float*)d_in[1];
  const float* b_up   = (const float*)d_in[2];
  const float* Wq     = (const float*)d_in[3];
  const float* bq     = (const float*)d_in[4];
  const float* Wk     = (const float*)d_in[5];
  const float* bk     = (const float*)d_in[6];
  const float* Wv     = (const float*)d_in[7];
  const float* bv     = (const float*)d_in[8];
  const float* conv_w = (const float*)d_in[9];
  const float* conv_b = (const float*)d_in[10];
  const float* W_ig   = (const float*)d_in[11];
  const float* b_ig   = (const float*)d_in[12];
  const float* W_fg   = (const float*)d_in[13];
  const float* b_fg   = (const float*)d_in[14];
  const float* norm_w = (const float*)d_in[15];
  const float* norm_b = (const float*)d_in[16];
  const float* skip   = (const float*)d_in[17];
  const float* W_down = (const float*)d_in[18];
  const float* b_down = (const float*)d_in[19];
  float* out = (float*)d_out;

  char* ws = (char*)d_ws;
  constexpr size_t OFF_XI  = 0;
  constexpr size_t OFF_CA  = OFF_XI + (size_t)NTOK * 1536 * 4;
  constexpr size_t OFF_QBF = OFF_CA + (size_t)NTOK * INNER_ * 4;
  constexpr size_t OFF_KBF = OFF_QBF + (size_t)16 * S_ * DH_ * 2;
  constexpr size_t OFF_VBF = OFF_KBF + (size_t)16 * S_ * DH_ * 2;
  constexpr size_t OFF_IG  = OFF_VBF + (size_t)16 * S_ * DH_ * 2;
  constexpr size_t OFF_FG  = OFF_IG + (size_t)16 * S_ * 4;
  constexpr size_t OFF_LFC = OFF_FG + (size_t)16 * S_ * 4;
  constexpr size_t OFF_AA  = OFF_LFC + (size_t)16 * S_ * 4;
  constexpr size_t OFF_RM  = OFF_AA + (size_t)16 * S_ * 4;
  constexpr size_t OFF_HS  = OFF_RM + (size_t)16 * S_ * 4;
  constexpr size_t OFF_XB  = OFF_HS + (size_t)NTOK * INNER_ * 4;
  constexpr size_t OFF_WUB = OFF_XB + (size_t)NTOK * DIM_ * 2;
  constexpr size_t OFF_PAC = OFF_WUB + (size_t)1536 * DIM_ * 2;
  constexpr size_t OFF_RSP = OFF_PAC + (size_t)16 * SLOTS_ * 64 * 192 * 4;
  constexpr size_t OFF_WDB = OFF_RSP + (size_t)16 * SLOTS_ * 64 * 4;
  constexpr size_t OFF_VTB = OFF_WDB + (size_t)DIM_ * INNER_ * 2;

  float* x_inner = (float*)(ws + OFF_XI);
  float* conv_a  = (float*)(ws + OFF_CA);
  __hip_bfloat16* qbf = (__hip_bfloat16*)(ws + OFF_QBF);
  __hip_bfloat16* kbf = (__hip_bfloat16*)(ws + OFF_KBF);
  __hip_bfloat16* vbf = (__hip_bfloat16*)(ws + OFF_VBF);
  float* ig  = (float*)(ws + OFF_IG);
  float* fg  = (float*)(ws + OFF_FG);
  float* lfc = (float*)(ws + OFF_LFC);
  float* aav = (float*)(ws + OFF_AA);
  float* rmv = (float*)(ws + OFF_RM);
  __hip_bfloat16* hsb = (__hip_bfloat16*)(ws + OFF_HS);
  __hip_bfloat16* xb  = (__hip_bfloat16*)(ws + OFF_XB);
  __hip_bfloat16* wub = (__hip_bfloat16*)(ws + OFF_WUB);
  float* pacc = (float*)(ws + OFF_PAC);
  float* rsp  = (float*)(ws + OFF_RSP);
  __hip_bfloat16* wdb = (__hip_bfloat16*)(ws + OFF_WDB);
  __hip_bfloat16* vtb = (__hip_bfloat16*)(ws + OFF_VTB);

  // 0) casts
  cast_bf16_k<<<(NTOK * DIM_ / 4 + 255) / 256, 256, 0, stream>>>(x, xb, NTOK * DIM_ / 4);
  cast_bf16_k<<<(1536 * DIM_ / 4 + 255) / 256, 256, 0, stream>>>(W_up, wub, 1536 * DIM_ / 4);
  cast_bf16_k<<<(DIM_ * INNER_ / 4 + 255) / 256, 256, 0, stream>>>(W_down, wdb, DIM_ * INNER_ / 4);
  // 1) up-projection (bf16 MFMA)
  gemm_up_k<<<dim3(12, 64), 256, 0, stream>>>(xb, wub, b_up, x_inner);
  // 2) depthwise conv + SiLU
  conv_silu_k<<<(NTOK * 192) / 256, 256, 0, stream>>>(x_inner, conv_w, conv_b, conv_a);
  // 3) headwise q,k,v + gates
  headwise_gates_k<<<NTOK, 256, 0, stream>>>(
      x_inner, conv_a, Wq, bq, Wk, bk, Wv, bv, W_ig, b_ig, W_fg, b_fg,
      qbf, kbf, vbf, ig, fg);
  // 3b) V transpose
  transpose_v_k<<<dim3(16, 3, 16), 256, 0, stream>>>(vbf, vtb);
  // 4) gate scans
  gate_scan_k<<<16, 64, 0, stream>>>(ig, fg, lfc, aav, rmv);
  // 5a) attention partials (LDS double-buffered staging)
  mlstm_part_k<<<dim3(SLOTS_, 16), 256, 0, stream>>>(qbf, kbf, vtb, aav, rmv, pacc, rsp);
  // 5b) reduce + epilogue
  mlstm_red_k<<<dim3(16, 16), 256, 0, stream>>>(
      pacc, rsp, lfc, rmv, conv_a, x_inner, norm_w, norm_b, skip, hsb);
  // 6) down-projection (bf16 MFMA, fp32 out)
  gemm_down_k<<<dim3(3, 64), 256, 0, stream>>>(hsb, wdb, b_down, out);
}

// Round 7
// 188.464 us; speedup vs baseline: 1.2781x; 1.0887x over previous
//
#include <hip/hip_runtime.h>
#include <hip/hip_bf16.h>

// ---------------------------------------------------------------------------
// ViLLayer forward, round 6:
//   - down-proj: split-K(4) partials (fp32, aliased onto dead pacc region)
//     + fully-unrolled 6-step K loop (54 hoistable loads) + float4 reduce.
//   - gemm_up: unroll hint for load/MFMA overlap.
// ---------------------------------------------------------------------------

#define B_     4
#define S_     1024
#define DIM_   384
#define INNER_ 768
#define NHM_   4
#define DH_    192
#define NTOK   (B_*S_)      // 4096
#define SLOTS_ 40           // sum over t of ceil((t+1)/4)

typedef __attribute__((ext_vector_type(8))) __bf16 bf16x8v;
typedef __attribute__((ext_vector_type(4))) float  f32x4;

static __device__ __forceinline__ f32x4 mfma16(bf16x8v a, bf16x8v b, f32x4 c) {
  return __builtin_amdgcn_mfma_f32_16x16x32_bf16(a, b, c, 0, 0, 0);
}

// ---------------- cast fp32 -> bf16 (vectorized) ---------------------------
__global__ __launch_bounds__(256) void cast_bf16_k(
    const float* __restrict__ in, __hip_bfloat16* __restrict__ out, int n4)
{
  const int i = blockIdx.x * 256 + threadIdx.x;
  if (i >= n4) return;
  const float4 v = *(const float4*)&in[i * 4];
  out[i * 4 + 0] = __float2bfloat16(v.x);
  out[i * 4 + 1] = __float2bfloat16(v.y);
  out[i * 4 + 2] = __float2bfloat16(v.z);
  out[i * 4 + 3] = __float2bfloat16(v.w);
}

// ---------------- up-proj: bf16 MFMA GEMM ----------------------------------
__global__ __launch_bounds__(256) void gemm_up_k(
    const __hip_bfloat16* __restrict__ xb, const __hip_bfloat16* __restrict__ Wb,
    const float* __restrict__ bias, float* __restrict__ C)
{
  const int n0 = blockIdx.x * 128, m0 = blockIdx.y * 64;
  const int wave = threadIdx.x >> 6, lane = threadIdx.x & 63;
  const int lrow = lane & 15, lgrp = lane >> 4;
  const __hip_bfloat16* xr = xb + (size_t)(m0 + wave * 16 + lrow) * DIM_;
  f32x4 acc[8];
  #pragma unroll
  for (int nt = 0; nt < 8; ++nt) acc[nt] = f32x4{0.f, 0.f, 0.f, 0.f};
  #pragma unroll 4
  for (int k0 = 0; k0 < DIM_; k0 += 32) {
    const bf16x8v af = *(const bf16x8v*)&xr[k0 + lgrp * 8];
    #pragma unroll
    for (int nt = 0; nt < 8; ++nt) {
      const bf16x8v bf = *(const bf16x8v*)
          &Wb[(size_t)(n0 + nt * 16 + lrow) * DIM_ + k0 + lgrp * 8];
      acc[nt] = mfma16(af, bf, acc[nt]);
    }
  }
  #pragma unroll
  for (int nt = 0; nt < 8; ++nt) {
    const int n = n0 + nt * 16 + lrow;
    const float bv = bias[n];
    #pragma unroll
    for (int r = 0; r < 4; ++r) {
      const int m = m0 + wave * 16 + lgrp * 4 + r;
      C[(size_t)m * 1536 + n] = acc[nt][r] + bv;
    }
  }
}

// ---------------- down-proj: split-K bf16 MFMA partials --------------------
// grid (3, 64, 4): z = K-part (K=192 each). pws[z][m][n] fp32 partial.
__global__ __launch_bounds__(256) void gemm_down_part_k(
    const __hip_bfloat16* __restrict__ hsb, const __hip_bfloat16* __restrict__ Wdb,
    float* __restrict__ pws)
{
  const int n0 = blockIdx.x * 128, m0 = blockIdx.y * 64;
  const int kbase = blockIdx.z * 192;
  const int wave = threadIdx.x >> 6, lane = threadIdx.x & 63;
  const int lrow = lane & 15, lgrp = lane >> 4;
  const __hip_bfloat16* ar = hsb + (size_t)(m0 + wave * 16 + lrow) * INNER_ + kbase;
  f32x4 acc[8];
  #pragma unroll
  for (int nt = 0; nt < 8; ++nt) acc[nt] = f32x4{0.f, 0.f, 0.f, 0.f};
  #pragma unroll
  for (int kc = 0; kc < 6; ++kc) {
    const bf16x8v af = *(const bf16x8v*)&ar[kc * 32 + lgrp * 8];
    #pragma unroll
    for (int nt = 0; nt < 8; ++nt) {
      const bf16x8v bf = *(const bf16x8v*)
          &Wdb[(size_t)(n0 + nt * 16 + lrow) * INNER_ + kbase + kc * 32 + lgrp * 8];
      acc[nt] = mfma16(af, bf, acc[nt]);
    }
  }
  float* po = pws + (size_t)blockIdx.z * NTOK * DIM_;
  #pragma unroll
  for (int nt = 0; nt < 8; ++nt) {
    const int n = n0 + nt * 16 + lrow;
    #pragma unroll
    for (int r = 0; r < 4; ++r) {
      const int m = m0 + wave * 16 + lgrp * 4 + r;
      po[(size_t)m * DIM_ + n] = acc[nt][r];
    }
  }
}

// ---------------- down-proj reduce: out = sum_z pws + bias -----------------
__global__ __launch_bounds__(256) void gemm_down_red_k(
    const float* __restrict__ pws, const float* __restrict__ bias,
    float* __restrict__ out)
{
  const int i = blockIdx.x * 256 + threadIdx.x;     // over NTOK*384/4
  if (i >= NTOK * DIM_ / 4) return;
  const int n4 = (i % (DIM_ / 4)) * 4;
  const float4 bv = *(const float4*)&bias[n4];
  float4 s0 = *(const float4*)&pws[(size_t)i * 4];
  const float4 s1 = *(const float4*)&pws[(size_t)NTOK * DIM_ * 1 + (size_t)i * 4];
  const float4 s2 = *(const float4*)&pws[(size_t)NTOK * DIM_ * 2 + (size_t)i * 4];
  const float4 s3 = *(const float4*)&pws[(size_t)NTOK * DIM_ * 3 + (size_t)i * 4];
  s0.x += s1.x + s2.x + s3.x + bv.x;
  s0.y += s1.y + s2.y + s3.y + bv.y;
  s0.z += s1.z + s2.z + s3.z + bv.z;
  s0.w += s1.w + s2.w + s3.w + bv.w;
  *(float4*)&out[(size_t)i * 4] = s0;
}

// ---------------- depthwise 3x3 conv + bias + SiLU (float4 channels) -------
__global__ __launch_bounds__(256) void conv_silu_k(
    const float* __restrict__ xi, const float* __restrict__ cw,
    const float* __restrict__ cb, float* __restrict__ ca)
{
  const int idx = blockIdx.x * 256 + threadIdx.x;     // over NTOK*192
  if (idx >= NTOK * 192) return;
  const int c4 = (idx % 192) * 4;
  const int t = idx / 192;
  const int s = t & 1023;
  const int y = s >> 5, x = s & 31;
  const int tb = t - s;
  float4 acc = *(const float4*)&cb[c4];
  #pragma unroll
  for (int ky = -1; ky <= 1; ++ky) {
    const int yy = y + ky;
    if (yy < 0 || yy > 31) continue;
    #pragma unroll
    for (int kx = -1; kx <= 1; ++kx) {
      const int xx = x + kx;
      if (xx < 0 || xx > 31) continue;
      const float4 v = *(const float4*)&xi[(size_t)(tb + (yy << 5) + xx) * 1536 + c4];
      const float4 w = *(const float4*)&cw[((ky + 1) * 3 + (kx + 1)) * INNER_ + c4];
      acc.x += v.x * w.x; acc.y += v.y * w.y;
      acc.z += v.z * w.z; acc.w += v.w * w.w;
    }
  }
  float4 o;
  o.x = acc.x / (1.f + __expf(-acc.x));
  o.y = acc.y / (1.f + __expf(-acc.y));
  o.z = acc.z / (1.f + __expf(-acc.z));
  o.w = acc.w / (1.f + __expf(-acc.w));
  *(float4*)&ca[(size_t)t * INNER_ + c4] = o;
}

// ---------------- headwise q,k,v + gate pre-activations --------------------
__global__ __launch_bounds__(256) void headwise_gates_k(
    const float* __restrict__ xi, const float* __restrict__ ca,
    const float* __restrict__ Wq, const float* __restrict__ bq,
    const float* __restrict__ Wk, const float* __restrict__ bk,
    const float* __restrict__ Wv, const float* __restrict__ bv,
    const float* __restrict__ Wig, const float* __restrict__ big,
    const float* __restrict__ Wfg, const float* __restrict__ bfg,
    __hip_bfloat16* __restrict__ qbf, __hip_bfloat16* __restrict__ kbf,
    __hip_bfloat16* __restrict__ vbf,
    float* __restrict__ ig, float* __restrict__ fg)
{
  __shared__ float qs[INNER_], ks[INNER_], vs[INNER_];
  const int t = blockIdx.x;
  const int b = t >> 10, s = t & 1023;
  const int tid = threadIdx.x;
  if (tid < 192) {
    float cav[4], xmv[4];
    #pragma unroll
    for (int d = 0; d < 4; ++d) {
      cav[d] = ca[(size_t)t * INNER_ + tid * 4 + d];
      xmv[d] = xi[(size_t)t * 1536 + tid * 4 + d];
    }
    #pragma unroll
    for (int o = 0; o < 4; ++o) {
      const int cidx = tid * 4 + o;
      float q = bq[cidx], k = bk[cidx], v = bv[cidx];
      #pragma unroll
      for (int d = 0; d < 4; ++d) {
        q += cav[d] * Wq[tid * 16 + o * 4 + d];
        k += cav[d] * Wk[tid * 16 + o * 4 + d];
        v += xmv[d] * Wv[tid * 16 + o * 4 + d];
      }
      qs[cidx] = q; ks[cidx] = k; vs[cidx] = v;
      const int hm = cidx / DH_, dd = cidx % DH_;
      const size_t o2 = ((size_t)(b * NHM_ + hm) * S_ + s) * DH_ + dd;
      qbf[o2] = __float2bfloat16(q);
      kbf[o2] = __float2bfloat16(k);
      vbf[o2] = __float2bfloat16(v);
    }
  }
  __syncthreads();
  const int g = tid >> 5, l32 = tid & 31;
  const float* Wg = (g < 4) ? Wig : Wfg;
  const int h = g & 3;
  float sum = 0.f;
  for (int c = l32; c < INNER_; c += 32) {
    sum += qs[c] * Wg[h * 2304 + c]
         + ks[c] * Wg[h * 2304 + 768 + c]
         + vs[c] * Wg[h * 2304 + 1536 + c];
  }
  #pragma unroll
  for (int m = 16; m >= 1; m >>= 1) sum += __shfl_xor(sum, m);
  if (l32 == 0) {
    if (g < 4) ig[(size_t)(b * NHM_ + h) * S_ + s] = sum + big[h];
    else       fg[(size_t)(b * NHM_ + h) * S_ + s] = sum + bfg[h];
  }
}

// ---------------- V transpose: vtb[bh][d][s] = vbf[bh][s][d] ---------------
__global__ __launch_bounds__(256) void transpose_v_k(
    const __hip_bfloat16* __restrict__ vbf, __hip_bfloat16* __restrict__ vtb)
{
  __shared__ __hip_bfloat16 tile[64][72];
  const int s0 = blockIdx.x * 64, d0 = blockIdx.y * 64, bh = blockIdx.z;
  const int tid = threadIdx.x;
  const int rr = tid >> 3;          // 0..31
  const int cc8 = (tid & 7) * 8;    // 0..56
  #pragma unroll
  for (int it = 0; it < 2; ++it) {
    const int r = rr + it * 32;
    *(bf16x8v*)&tile[r][cc8] =
        *(const bf16x8v*)&vbf[((size_t)bh * S_ + s0 + r) * DH_ + d0 + cc8];
  }
  __syncthreads();
  #pragma unroll
  for (int it = 0; it < 2; ++it) {
    const int r = rr + it * 32;     // d_local
    bf16x8v tmp;
    #pragma unroll
    for (int e = 0; e < 8; ++e) tmp[e] = *(__bf16*)&tile[cc8 + e][r];
    *(bf16x8v*)&vtb[((size_t)bh * DH_ + d0 + r) * S_ + s0 + cc8] = tmp;
  }
}

// ---------------- per-(b,h) scans ------------------------------------------
__global__ __launch_bounds__(64) void gate_scan_k(
    const float* __restrict__ ig, const float* __restrict__ fg,
    float* __restrict__ lfc, float* __restrict__ aa, float* __restrict__ rm)
{
  const int bh = blockIdx.x;
  const int lane = threadIdx.x;
  const float* fgp = fg + bh * S_;
  const float* igp = ig + bh * S_;
  float v[16];
  float run = 0.f;
  #pragma unroll
  for (int i = 0; i < 16; ++i) {
    const float x = fgp[lane * 16 + i];
    const float lf = fminf(x, 0.f) - log1pf(expf(-fabsf(x)));
    run += lf;
    v[i] = run;
  }
  float inc = run;
  #pragma unroll
  for (int off = 1; off < 64; off <<= 1) {
    const float o = __shfl_up(inc, off);
    if (lane >= off) inc += o;
  }
  const float excl = inc - run;
  float rv[16];
  float rmx = -INFINITY;
  #pragma unroll
  for (int i = 0; i < 16; ++i) {
    const float l = v[i] + excl;
    lfc[bh * S_ + lane * 16 + i] = l;
    const float a = igp[lane * 16 + i] - l;
    aa[bh * S_ + lane * 16 + i] = a;
    rmx = fmaxf(rmx, a);
    rv[i] = rmx;
  }
  float incm = rmx;
  #pragma unroll
  for (int off = 1; off < 64; off <<= 1) {
    const float o = __shfl_up(incm, off);
    if (lane >= off) incm = fmaxf(incm, o);
  }
  float exm = __shfl_up(incm, 1);
  if (lane == 0) exm = -INFINITY;
  #pragma unroll
  for (int i = 0; i < 16; ++i) {
    rm[bh * S_ + lane * 16 + i] = fmaxf(rv[i], exm);
  }
}

// ---------------- mLSTM attention: partial kernel --------------------------
__global__ __launch_bounds__(256) void mlstm_part_k(
    const __hip_bfloat16* __restrict__ qbf, const __hip_bfloat16* __restrict__ kbf,
    const __hip_bfloat16* __restrict__ vtb,
    const float* __restrict__ aa, const float* __restrict__ rm,
    float* __restrict__ pacc, float* __restrict__ rsp)
{
  __shared__ __hip_bfloat16 Kl[2][6144];
  __shared__ __hip_bfloat16 Vl[2][6144];
  __shared__ __hip_bfloat16 Pl[4][16][40];
  const int bh = blockIdx.y;
  const int slot = blockIdx.x;
  int t = 0, base = 0;
  #pragma unroll
  for (int s = 0; s < 16; ++s) {
    const int sz = (s >> 2) + 1;
    if (slot >= base + sz) { base += sz; t = s + 1; }
  }
  const int c = slot - base;
  const int jt_lo = c * 8;
  const int jt_hi = min(jt_lo + 8, 2 * t + 2);

  const int wave = threadIdx.x >> 6, lane = threadIdx.x & 63;
  const int lrow = lane & 15, lgrp = lane >> 4;
  const int q0 = t * 64 + wave * 16;
  const __hip_bfloat16* Q  = qbf + (size_t)bh * S_ * DH_;
  const __hip_bfloat16* Kp = kbf + (size_t)bh * S_ * DH_;
  const __hip_bfloat16* VT = vtb + (size_t)bh * DH_ * S_;
  const float* aap = aa + bh * S_;
  const float* rmp = rm + bh * S_;

  bf16x8v qf[6];
  #pragma unroll
  for (int kk = 0; kk < 6; ++kk)
    qf[kk] = *(const bf16x8v*)&Q[(size_t)(q0 + lrow) * DH_ + kk * 32 + lgrp * 8];
  float rmi[4];
  #pragma unroll
  for (int r = 0; r < 4; ++r) rmi[r] = rmp[q0 + lgrp * 4 + r];

  const f32x4 zero4 = {0.f, 0.f, 0.f, 0.f};
  f32x4 hacc[12];
  #pragma unroll
  for (int dd = 0; dd < 12; ++dd) hacc[dd] = zero4;
  float rs[4] = {0.f, 0.f, 0.f, 0.f};
  const float scale = 0.07216878364870323f;   // 1/sqrt(192)
  const int myqmax = q0 + 15;

  bf16x8v kreg[3], vreg[3];
  const int s0_ = wave * 192 + lane;

  auto stage_load = [&](int j0s) {
    #pragma unroll
    for (int i = 0; i < 3; ++i) {
      const int s = s0_ + i * 64;
      const int kk = s >> 7, jr = (s >> 2) & 31, g = s & 3;
      kreg[i] = *(const bf16x8v*)&Kp[(size_t)(j0s + jr) * DH_ + kk * 32 + g * 8];
      const int d = s >> 2;
      vreg[i] = *(const bf16x8v*)&VT[(size_t)d * S_ + j0s + g * 8];
    }
  };
  auto stage_write = [&](int buf) {
    #pragma unroll
    for (int i = 0; i < 3; ++i) {
      const int s = s0_ + i * 64;
      *(bf16x8v*)&Kl[buf][s << 3] = kreg[i];
      *(bf16x8v*)&Vl[buf][s << 3] = vreg[i];
    }
  };

  stage_load(jt_lo * 32);
  stage_write(0);
  __syncthreads();
  int cur = 0;

  for (int jt = jt_lo; jt < jt_hi; ++jt) {
    const int j0 = jt * 32;
    const bool nxt = (jt + 1 < jt_hi);
    if (nxt) stage_load((jt + 1) * 32);
    if (j0 <= myqmax) {
      f32x4 sacc[2];
      sacc[0] = zero4; sacc[1] = zero4;
      #pragma unroll
      for (int jj = 0; jj < 2; ++jj) {
        #pragma unroll
        for (int kk = 0; kk < 6; ++kk) {
          const bf16x8v kf = *(const bf16x8v*)
              &Kl[cur][(kk * 128 + (jj * 16 + lrow) * 4 + lgrp) << 3];
          sacc[jj] = mfma16(qf[kk], kf, sacc[jj]);
        }
      }
      #pragma unroll
      for (int jj = 0; jj < 2; ++jj) {
        const int j = j0 + jj * 16 + lrow;
        const float ajv = aap[j];
        #pragma unroll
        for (int r = 0; r < 4; ++r) {
          const int i_ = q0 + lgrp * 4 + r;
          float cval = 0.f;
          if (j <= i_) cval = sacc[jj][r] * scale * __expf(ajv - rmi[r]);
          rs[r] += cval;
          Pl[wave][lgrp * 4 + r][jj * 16 + lrow] = __float2bfloat16(cval);
        }
      }
      const bf16x8v pf = *(const bf16x8v*)&Pl[wave][lrow][lgrp * 8];
      #pragma unroll
      for (int dd = 0; dd < 12; ++dd) {
        const bf16x8v vf = *(const bf16x8v*)
            &Vl[cur][(dd * 64 + lrow * 4 + lgrp) << 3];
        hacc[dd] = mfma16(pf, vf, hacc[dd]);
      }
    }
    if (nxt) stage_write(cur ^ 1);
    __syncthreads();
    cur ^= 1;
  }

  #pragma unroll
  for (int r = 0; r < 4; ++r) {
    #pragma unroll
    for (int m = 1; m < 16; m <<= 1) rs[r] += __shfl_xor(rs[r], m);
  }
  const size_t pb16 = ((size_t)bh * SLOTS_ + slot) * 16 + wave * 4 + lgrp;
  #pragma unroll
  for (int dd = 0; dd < 12; ++dd) {
    *(f32x4*)&pacc[(pb16 * 12 + dd) * 64 + lrow * 4] = hacc[dd];
  }
  if (lrow == 0) {
    #pragma unroll
    for (int r = 0; r < 4; ++r)
      rsp[((size_t)bh * SLOTS_ + slot) * 64 + wave * 16 + lgrp * 4 + r] = rs[r];
  }
}

// ---------------- mLSTM reduce + fused epilogue (bf16 h_state out) ---------
__global__ __launch_bounds__(256) void mlstm_red_k(
    const float* __restrict__ pacc, const float* __restrict__ rsp,
    const float* __restrict__ lfc, const float* __restrict__ rm,
    const float* __restrict__ ca, const float* __restrict__ xi,
    const float* __restrict__ nw, const float* __restrict__ nb,
    const float* __restrict__ skip, __hip_bfloat16* __restrict__ hs)
{
  const int t = blockIdx.x, bh = blockIdx.y;
  const int b = bh >> 2, hm = bh & 3;
  int base = 0;
  #pragma unroll
  for (int s = 0; s < 16; ++s) if (s < t) base += (s >> 2) + 1;
  const int nc = (t >> 2) + 1;

  const int wave = threadIdx.x >> 6, lane = threadIdx.x & 63;
  const int lrow = lane & 15, lgrp = lane >> 4;
  const int q0 = t * 64 + wave * 16;
  const float* lfcp = lfc + bh * S_;
  const float* rmp  = rm + bh * S_;

  f32x4 hsum[12];
  #pragma unroll
  for (int dd = 0; dd < 12; ++dd) hsum[dd] = f32x4{0.f, 0.f, 0.f, 0.f};
  float rst[4] = {0.f, 0.f, 0.f, 0.f};

  for (int cc = 0; cc < nc; ++cc) {
    const size_t pb16 = ((size_t)bh * SLOTS_ + base + cc) * 16 + wave * 4 + lgrp;
    #pragma unroll
    for (int dd = 0; dd < 12; ++dd) {
      const f32x4 p = *(const f32x4*)&pacc[(pb16 * 12 + dd) * 64 + lrow * 4];
      hsum[dd] += p;
    }
    #pragma unroll
    for (int r = 0; r < 4; ++r)
      rst[r] += rsp[((size_t)bh * SLOTS_ + base + cc) * 64 + wave * 16 + lgrp * 4 + r];
  }

  #pragma unroll
  for (int r = 0; r < 4; ++r) {
    const int i_ = q0 + lgrp * 4 + r;
    const int tok = b * S_ + i_;
    const float mld = lfcp[i_] + rmp[i_];
    const float nrm = fmaxf(fabsf(rst[r]), __expf(-mld)) + 1e-6f;
    float hv[12];
    float sum = 0.f, sq = 0.f;
    #pragma unroll
    for (int dd = 0; dd < 12; ++dd) {
      const float x = hsum[dd][r] / nrm;
      hv[dd] = x; sum += x; sq += x * x;
    }
    #pragma unroll
    for (int m = 1; m < 16; m <<= 1) {
      sum += __shfl_xor(sum, m);
      sq  += __shfl_xor(sq, m);
    }
    const float mean = sum * (1.f / 192.f);
    const float var  = sq * (1.f / 192.f) - mean * mean;
    const float rstd = rsqrtf(var + 1e-5f);
    #pragma unroll
    for (int dd = 0; dd < 12; ++dd) {
      const int cidx = hm * DH_ + dd * 16 + lrow;
      const float hn = (hv[dd] - mean) * rstd * nw[cidx] + nb[cidx];
      const float cav = ca[(size_t)tok * INNER_ + cidx];
      const float zz  = xi[(size_t)tok * 1536 + 768 + cidx];
      const float hsv = (hn + skip[cidx] * cav) * (zz / (1.f + __expf(-zz)));
      hs[(size_t)tok * INNER_ + cidx] = __float2bfloat16(hsv);
    }
  }
}

// ---------------------------------------------------------------------------
extern "C" void kernel_launch(void* const* d_in, const int* in_sizes, int n_in,
                              void* d_out, int out_size, void* d_ws, size_t ws_size,
                              hipStream_t stream) {
  const float* x      = (const float*)d_in[0];
  const float* W_up   = (const float*)d_in[1];
  const float* b_up   = (const float*)d_in[2];
  const float* Wq     = (const float*)d_in[3];
  const float* bq     = (const float*)d_in[4];
  const float* Wk     = (const float*)d_in[5];
  const float* bk     = (const float*)d_in[6];
  const float* Wv     = (const float*)d_in[7];
  const float* bv     = (const float*)d_in[8];
  const float* conv_w = (const float*)d_in[9];
  const float* conv_b = (const float*)d_in[10];
  const float* W_ig   = (const float*)d_in[11];
  const float* b_ig   = (const float*)d_in[12];
  const float* W_fg   = (const float*)d_in[13];
  const float* b_fg   = (const float*)d_in[14];
  const float* norm_w = (const float*)d_in[15];
  const float* norm_b = (const float*)d_in[16];
  const float* skip   = (const float*)d_in[17];
  const float* W_down = (const float*)d_in[18];
  const float* b_down = (const float*)d_in[19];
  float* out = (float*)d_out;

  char* ws = (char*)d_ws;
  constexpr size_t OFF_XI  = 0;
  constexpr size_t OFF_CA  = OFF_XI + (size_t)NTOK * 1536 * 4;
  constexpr size_t OFF_QBF = OFF_CA + (size_t)NTOK * INNER_ * 4;
  constexpr size_t OFF_KBF = OFF_QBF + (size_t)16 * S_ * DH_ * 2;
  constexpr size_t OFF_VBF = OFF_KBF + (size_t)16 * S_ * DH_ * 2;
  constexpr size_t OFF_IG  = OFF_VBF + (size_t)16 * S_ * DH_ * 2;
  constexpr size_t OFF_FG  = OFF_IG + (size_t)16 * S_ * 4;
  constexpr size_t OFF_LFC = OFF_FG + (size_t)16 * S_ * 4;
  constexpr size_t OFF_AA  = OFF_LFC + (size_t)16 * S_ * 4;
  constexpr size_t OFF_RM  = OFF_AA + (size_t)16 * S_ * 4;
  constexpr size_t OFF_HS  = OFF_RM + (size_t)16 * S_ * 4;
  constexpr size_t OFF_XB  = OFF_HS + (size_t)NTOK * INNER_ * 4;
  constexpr size_t OFF_WUB = OFF_XB + (size_t)NTOK * DIM_ * 2;
  constexpr size_t OFF_PAC = OFF_WUB + (size_t)1536 * DIM_ * 2;
  constexpr size_t OFF_RSP = OFF_PAC + (size_t)16 * SLOTS_ * 64 * 192 * 4;
  constexpr size_t OFF_WDB = OFF_RSP + (size_t)16 * SLOTS_ * 64 * 4;
  constexpr size_t OFF_VTB = OFF_WDB + (size_t)DIM_ * INNER_ * 2;

  float* x_inner = (float*)(ws + OFF_XI);
  float* conv_a  = (float*)(ws + OFF_CA);
  __hip_bfloat16* qbf = (__hip_bfloat16*)(ws + OFF_QBF);
  __hip_bfloat16* kbf = (__hip_bfloat16*)(ws + OFF_KBF);
  __hip_bfloat16* vbf = (__hip_bfloat16*)(ws + OFF_VBF);
  float* ig  = (float*)(ws + OFF_IG);
  float* fg  = (float*)(ws + OFF_FG);
  float* lfc = (float*)(ws + OFF_LFC);
  float* aav = (float*)(ws + OFF_AA);
  float* rmv = (float*)(ws + OFF_RM);
  __hip_bfloat16* hsb = (__hip_bfloat16*)(ws + OFF_HS);
  __hip_bfloat16* xb  = (__hip_bfloat16*)(ws + OFF_XB);
  __hip_bfloat16* wub = (__hip_bfloat16*)(ws + OFF_WUB);
  float* pacc = (float*)(ws + OFF_PAC);
  float* rsp  = (float*)(ws + OFF_RSP);
  __hip_bfloat16* wdb = (__hip_bfloat16*)(ws + OFF_WDB);
  __hip_bfloat16* vtb = (__hip_bfloat16*)(ws + OFF_VTB);
  // split-K partials alias the pacc region (dead after mlstm_red_k):
  // need 4 * 4096 * 384 * 4 = 25.2 MB <= pacc's 31.5 MB
  float* pws = pacc;

  // 0) casts
  cast_bf16_k<<<(NTOK * DIM_ / 4 + 255) / 256, 256, 0, stream>>>(x, xb, NTOK * DIM_ / 4);
  cast_bf16_k<<<(1536 * DIM_ / 4 + 255) / 256, 256, 0, stream>>>(W_up, wub, 1536 * DIM_ / 4);
  cast_bf16_k<<<(DIM_ * INNER_ / 4 + 255) / 256, 256, 0, stream>>>(W_down, wdb, DIM_ * INNER_ / 4);
  // 1) up-projection (bf16 MFMA)
  gemm_up_k<<<dim3(12, 64), 256, 0, stream>>>(xb, wub, b_up, x_inner);
  // 2) depthwise conv + SiLU
  conv_silu_k<<<(NTOK * 192) / 256, 256, 0, stream>>>(x_inner, conv_w, conv_b, conv_a);
  // 3) headwise q,k,v + gates
  headwise_gates_k<<<NTOK, 256, 0, stream>>>(
      x_inner, conv_a, Wq, bq, Wk, bk, Wv, bv, W_ig, b_ig, W_fg, b_fg,
      qbf, kbf, vbf, ig, fg);
  // 3b) V transpose
  transpose_v_k<<<dim3(16, 3, 16), 256, 0, stream>>>(vbf, vtb);
  // 4) gate scans
  gate_scan_k<<<16, 64, 0, stream>>>(ig, fg, lfc, aav, rmv);
  // 5a) attention partials
  mlstm_part_k<<<dim3(SLOTS_, 16), 256, 0, stream>>>(qbf, kbf, vtb, aav, rmv, pacc, rsp);
  // 5b) reduce + epilogue
  mlstm_red_k<<<dim3(16, 16), 256, 0, stream>>>(
      pacc, rsp, lfc, rmv, conv_a, x_inner, norm_w, norm_b, skip, hsb);
  // 6) down-projection: split-K partials + reduce
  gemm_down_part_k<<<dim3(3, 64, 4), 256, 0, stream>>>(hsb, wdb, pws);
  gemm_down_red_k<<<(NTOK * DIM_ / 4 + 255) / 256, 256, 0, stream>>>(pws, b_down, out);
}